// Round 13
// baseline (418.967 us; speedup 1.0000x reference)
//
#include <hip/hip_runtime.h>

#define N_NODES   100000
#define N_EDGES   1600000
#define NFEAT     128
#define N_GRAPHS  1024

// ---- bucketed CSR build (256-node buckets, block-local counting-sort scatter) ----
#define BSHIFT  8
#define BNODES  256
#define NBUCK   391                  // ceil(100000 / 256)
#define BCAP    4608                 // mean 4096 + 8 sigma
#define SC_EDGES 8192
#define SC_BLOCKS 196                // ceil(1.6M / 8192)

typedef unsigned int uint32;
typedef unsigned short ushort;
typedef __attribute__((ext_vector_type(8))) short short8;   // 8 bf16 (4 VGPRs)
typedef __attribute__((ext_vector_type(4))) float f32x4;

// fp32 -> bf16 bits, round-to-nearest-even (finite inputs)
__device__ inline ushort f2b(float f) {
    uint32 x = __float_as_uint(f);
    uint32 r = x + 0x7fffu + ((x >> 16) & 1u);
    return (ushort)(r >> 16);
}
__device__ inline float blo(uint32 u) { return __uint_as_float(u << 16); }
__device__ inline float bhi(uint32 u) { return __uint_as_float(u & 0xffff0000u); }

// ---------------- scatter: block-local counting sort -> burst writes, 1 atomic per (block,bin) ----------------
__global__ __launch_bounds__(256) void k_scatter(const int* __restrict__ src, const int* __restrict__ dst,
                                                 int* __restrict__ cur, uint32* __restrict__ bbuf) {
    __shared__ int hist[NBUCK];
    __shared__ int lofs[NBUCK];
    __shared__ int lcur[NBUCK];
    __shared__ int gbase[NBUCK];
    __shared__ int wsum[4];
    __shared__ uint32 sortedP[SC_EDGES];   // 32 KB
    __shared__ ushort sortedB[SC_EDGES];   // 16 KB
    int t = threadIdx.x;
    int e0 = blockIdx.x * SC_EDGES;
    int total = N_EDGES - e0; if (total > SC_EDGES) total = SC_EDGES; if (total < 0) total = 0;

    for (int i = t; i < NBUCK; i += 256) hist[i] = 0;
    __syncthreads();
    for (int i = t; i < total; i += 256)
        atomicAdd(&hist[dst[e0 + i] >> BSHIFT], 1);
    __syncthreads();
    {
        int b0 = 2 * t, b1 = 2 * t + 1;
        int h0 = (b0 < NBUCK) ? hist[b0] : 0;
        int h1 = (b1 < NBUCK) ? hist[b1] : 0;
        int ts = h0 + h1;
        int lane = t & 63, w = t >> 6;
        int inc = ts;
        #pragma unroll
        for (int d = 1; d < 64; d <<= 1) {
            int u = __shfl_up(inc, d, 64);
            if (lane >= d) inc += u;
        }
        if (lane == 63) wsum[w] = inc;
        __syncthreads();
        int wpre = 0;
        for (int i = 0; i < w; ++i) wpre += wsum[i];
        int run = wpre + inc - ts;
        if (b0 < NBUCK) {
            lofs[b0] = run; lcur[b0] = run;
            if (h0) gbase[b0] = atomicAdd(&cur[b0], h0);
        }
        if (b1 < NBUCK) {
            lofs[b1] = run + h0; lcur[b1] = run + h0;
            if (h1) gbase[b1] = atomicAdd(&cur[b1], h1);
        }
    }
    __syncthreads();
    for (int i = t; i < total; i += 256) {
        int s = src[e0 + i], d = dst[e0 + i];
        int b = d >> BSHIFT;
        int p = atomicAdd(&lcur[b], 1);
        sortedP[p] = ((uint32)(d & (BNODES - 1)) << 17) | (uint32)s;
        sortedB[p] = (ushort)b;
    }
    __syncthreads();
    for (int i = t; i < total; i += 256) {
        int b = sortedB[i];
        int addr = gbase[b] + (i - lofs[b]);
        if (addr < BCAP)
            bbuf[(size_t)b * BCAP + addr] = sortedP[i];
    }
}

// ---------------- per-bucket counting sort -> CSR col + offsets + dinv ----------------
// (bucketBase prefix computed in-block: each block sums min(cur[i],BCAP) for i < b)
__global__ __launch_bounds__(256) void k_build(const uint32* __restrict__ bbuf, const int* __restrict__ cur,
                                               int* __restrict__ col, int* __restrict__ offsets,
                                               float* __restrict__ dinv) {
    int b = blockIdx.x;
    __shared__ int hist[BNODES], lcur[BNODES];
    __shared__ int wsum[4], wtot[4];
    __shared__ int sorted[BCAP];              // 18 KB
    __shared__ int sBase, sTotal;
    int t = threadIdx.x;
    // ---- in-block bucket prefix: pre = sum_{i<b} min(cur[i],BCAP); tot = sum_all ----
    {
        int pre = 0, tot = 0;
        #pragma unroll
        for (int q = 0; q < 2; ++q) {
            int i = 2 * t + q;
            if (i < NBUCK) {
                int v = cur[i]; if (v > BCAP) v = BCAP;
                tot += v;
                if (i < b) pre += v;
            }
        }
        int lane = t & 63, w = t >> 6;
        #pragma unroll
        for (int d = 32; d > 0; d >>= 1) { pre += __shfl_down(pre, d, 64); tot += __shfl_down(tot, d, 64); }
        if (lane == 0) { wsum[w] = pre; wtot[w] = tot; }
        __syncthreads();
        if (t == 0) {
            sBase = wsum[0] + wsum[1] + wsum[2] + wsum[3];
            sTotal = wtot[0] + wtot[1] + wtot[2] + wtot[3];
        }
        hist[t] = 0;
    }
    __syncthreads();
    int base = sBase;
    if (b == NBUCK - 1 && t == 0) offsets[N_NODES] = sTotal;
    int cnt = cur[b]; if (cnt > BCAP) cnt = BCAP;
    const uint32* reg = bbuf + (size_t)b * BCAP;
    for (int i = t; i < cnt; i += 256) atomicAdd(&hist[reg[i] >> 17], 1);
    __syncthreads();
    {
        int c = hist[t];
        int lane = t & 63, w = t >> 6;
        int inc = c;
        #pragma unroll
        for (int d = 1; d < 64; d <<= 1) {
            int u = __shfl_up(inc, d, 64);
            if (lane >= d) inc += u;
        }
        if (lane == 63) wsum[w] = inc;
        __syncthreads();
        int wpre = 0;
        for (int i = 0; i < w; ++i) wpre += wsum[i];
        int excl = wpre + inc - c;
        lcur[t] = excl;
        int node = (b << BSHIFT) + t;
        if (node < N_NODES) {
            offsets[node] = base + excl;
            dinv[node] = rsqrtf((float)(c + 1));
        }
    }
    __syncthreads();
    for (int i = t; i < cnt; i += 256) {
        uint32 p = reg[i];
        int lp = atomicAdd(&lcur[p >> 17], 1);
        sorted[lp] = (int)(p & 0x1FFFF);
    }
    __syncthreads();
    for (int i = t; i < cnt; i += 256) col[base + i] = sorted[i];
}

// ---------------- bf16 MFMA GEMM: C[M,128] = A[M,128] @ W (W fp32, cast fused) ----------------
// 512 thr / 8 waves. W staged+transposed to LDS once per block; each wave loads its
// B-fragments (half the cols, 64 VGPR) ONCE into registers, then loops 4 row-tiles
// of 64 rows (256 rows/block). Epilogue via 16KB LDS C-tile -> coalesced float4.
#define WT_STRIDE 136
#define GEMM_TILES 4

#define GEMM_PROLOGUE(AFRAG_LOADS) \
    __shared__ ushort sWT[NFEAT * WT_STRIDE];   /* 34 KB  [n][k] bf16 */ \
    __shared__ ushort sC[64 * NFEAT];           /* 16 KB */ \
    int t = threadIdx.x; \
    /* stage W fp32 [k][n] -> sWT bf16 [n][k] */ \
    for (int i = t; i < NFEAT * 32; i += 512) { \
        int k = i >> 5, n0 = (i & 31) * 4; \
        float4 v = ((const float4*)Wl)[i]; \
        sWT[(n0 + 0) * WT_STRIDE + k] = f2b(v.x); \
        sWT[(n0 + 1) * WT_STRIDE + k] = f2b(v.y); \
        sWT[(n0 + 2) * WT_STRIDE + k] = f2b(v.z); \
        sWT[(n0 + 3) * WT_STRIDE + k] = f2b(v.w); \
    } \
    int wave = t >> 6, lane = t & 63; \
    int ch = wave & 1;          /* column half */ \
    int rg = wave >> 1;         /* row group 0..3 */ \
    int kg = lane >> 4; \
    int colBase = lane & 15; \
    __syncthreads(); \
    /* B fragments: 4 nt x 4 k-chunks, registers (64 VGPR) */ \
    short8 bfr[4][4]; \
    _Pragma("unroll") \
    for (int nt = 0; nt < 4; ++nt) { \
        int n = ch * 64 + nt * 16 + colBase; \
        const short8* Bp = (const short8*)(sWT + n * WT_STRIDE + kg * 8); \
        bfr[nt][0] = Bp[0]; bfr[nt][1] = Bp[4]; bfr[nt][2] = Bp[8]; bfr[nt][3] = Bp[12]; \
    } \
    int blockBase = blockIdx.x * (64 * GEMM_TILES); \
    for (int tile = 0; tile < GEMM_TILES; ++tile) { \
        int tb = blockBase + tile * 64; \
        int m0 = tb + rg * 16; \
        int mRow = m0 + colBase; \
        if (mRow >= M) mRow = M - 1; \
        short8 a0, a1, a2, a3; \
        AFRAG_LOADS \
        f32x4 acc[4]; \
        _Pragma("unroll") \
        for (int nt = 0; nt < 4; ++nt) acc[nt] = (f32x4){0.f, 0.f, 0.f, 0.f}; \
        _Pragma("unroll") \
        for (int nt = 0; nt < 4; ++nt) { \
            acc[nt] = __builtin_amdgcn_mfma_f32_16x16x32_bf16(a0, bfr[nt][0], acc[nt], 0, 0, 0); \
            acc[nt] = __builtin_amdgcn_mfma_f32_16x16x32_bf16(a1, bfr[nt][1], acc[nt], 0, 0, 0); \
            acc[nt] = __builtin_amdgcn_mfma_f32_16x16x32_bf16(a2, bfr[nt][2], acc[nt], 0, 0, 0); \
            acc[nt] = __builtin_amdgcn_mfma_f32_16x16x32_bf16(a3, bfr[nt][3], acc[nt], 0, 0, 0); \
        } \
        __syncthreads();   /* prior tile's sC reads done; safe to rewrite */ \
        _Pragma("unroll") \
        for (int r = 0; r < 4; ++r) { \
            int rowLocal = rg * 16 + kg * 4 + r; \
            _Pragma("unroll") \
            for (int nt = 0; nt < 4; ++nt) \
                sC[rowLocal * NFEAT + ch * 64 + nt * 16 + colBase] = f2b(acc[nt][r]); \
        } \
        __syncthreads(); \
        const float4* sC4 = (const float4*)sC; \
        for (int i = t; i < 1024; i += 512) { \
            int row = i >> 4; \
            int gr = tb + row; \
            if (gr < M) ((float4*)(C + (size_t)gr * NFEAT))[i & 15] = sC4[i]; \
        } \
    }

__global__ __launch_bounds__(512) void k_gemm(const ushort* __restrict__ A,
                                              const float* __restrict__ Wl,
                                              ushort* __restrict__ C, int M) {
    GEMM_PROLOGUE({
        const short8* Ap = (const short8*)(A + (size_t)mRow * NFEAT + kg * 8);
        a0 = Ap[0]; a1 = Ap[4]; a2 = Ap[8]; a3 = Ap[12];
    })
}

__device__ inline short8 cvt8(const float* p) {
    float4 v0 = ((const float4*)p)[0];
    float4 v1 = ((const float4*)p)[1];
    short8 r;
    r[0] = (short)f2b(v0.x); r[1] = (short)f2b(v0.y);
    r[2] = (short)f2b(v0.z); r[3] = (short)f2b(v0.w);
    r[4] = (short)f2b(v1.x); r[5] = (short)f2b(v1.y);
    r[6] = (short)f2b(v1.z); r[7] = (short)f2b(v1.w);
    return r;
}

__global__ __launch_bounds__(512) void k_gemm_x(const float* __restrict__ A,
                                                const float* __restrict__ Wl,
                                                ushort* __restrict__ C, int M) {
    GEMM_PROLOGUE({
        const float* Ap = A + (size_t)mRow * NFEAT + kg * 8;
        a0 = cvt8(Ap); a1 = cvt8(Ap + 32); a2 = cvt8(Ap + 64); a3 = cvt8(Ap + 96);
    })
}

// ---------------- aggregation core: 4 edges per uint4 gather instruction ----------------
#define AGG_BODY4 \
    float dn = dinv[n]; \
    int half = lane >> 4; \
    int fl = lane & 15; \
    const uint4* XW4 = (const uint4*)XWu; \
    uint4 sv = XW4[(size_t)n * 16 + fl]; \
    float ws = (half == 0) ? dn * dn : 0.f; \
    float a0 = ws * blo(sv.x), a1 = ws * bhi(sv.x); \
    float a2 = ws * blo(sv.y), a3 = ws * bhi(sv.y); \
    float a4 = ws * blo(sv.z), a5 = ws * bhi(sv.z); \
    float a6 = ws * blo(sv.w), a7 = ws * bhi(sv.w); \
    int e0 = off[n], e1 = off[n + 1]; \
    for (int base = e0; base < e1; base += 64) { \
        int len = e1 - base; if (len > 64) len = 64; \
        int cm = (lane < len) ? col[base + lane] : 0; \
        float wm = (lane < len) ? dn * dinv[cm] : 0.f; \
        int j = 0; \
        for (; j + 16 <= len; j += 16) { \
            uint4 u[4]; float w[4]; \
            _Pragma("unroll") \
            for (int p = 0; p < 4; ++p) { \
                int idx = j + 4 * p + half; \
                int cc = __shfl(cm, idx, 64); \
                w[p] = __shfl(wm, idx, 64); \
                u[p] = XW4[(size_t)cc * 16 + fl]; \
            } \
            _Pragma("unroll") \
            for (int p = 0; p < 4; ++p) { \
                a0 = fmaf(w[p], blo(u[p].x), a0); a1 = fmaf(w[p], bhi(u[p].x), a1); \
                a2 = fmaf(w[p], blo(u[p].y), a2); a3 = fmaf(w[p], bhi(u[p].y), a3); \
                a4 = fmaf(w[p], blo(u[p].z), a4); a5 = fmaf(w[p], bhi(u[p].z), a5); \
                a6 = fmaf(w[p], blo(u[p].w), a6); a7 = fmaf(w[p], bhi(u[p].w), a7); \
            } \
        } \
        for (; j < len; j += 4) { \
            int rem = len - j; \
            int idx = j + ((half < rem) ? half : 0); \
            int cc = __shfl(cm, idx, 64); \
            float ww = __shfl(wm, idx, 64); \
            if (half >= rem) ww = 0.f; \
            uint4 u = XW4[(size_t)cc * 16 + fl]; \
            a0 = fmaf(ww, blo(u.x), a0); a1 = fmaf(ww, bhi(u.x), a1); \
            a2 = fmaf(ww, blo(u.y), a2); a3 = fmaf(ww, bhi(u.y), a3); \
            a4 = fmaf(ww, blo(u.z), a4); a5 = fmaf(ww, bhi(u.z), a5); \
            a6 = fmaf(ww, blo(u.w), a6); a7 = fmaf(ww, bhi(u.w), a7); \
        } \
    } \
    a0 += __shfl_xor(a0, 32, 64); a0 += __shfl_xor(a0, 16, 64); \
    a1 += __shfl_xor(a1, 32, 64); a1 += __shfl_xor(a1, 16, 64); \
    a2 += __shfl_xor(a2, 32, 64); a2 += __shfl_xor(a2, 16, 64); \
    a3 += __shfl_xor(a3, 32, 64); a3 += __shfl_xor(a3, 16, 64); \
    a4 += __shfl_xor(a4, 32, 64); a4 += __shfl_xor(a4, 16, 64); \
    a5 += __shfl_xor(a5, 32, 64); a5 += __shfl_xor(a5, 16, 64); \
    a6 += __shfl_xor(a6, 32, 64); a6 += __shfl_xor(a6, 16, 64); \
    a7 += __shfl_xor(a7, 32, 64); a7 += __shfl_xor(a7, 16, 64);

__global__ __launch_bounds__(256) void k_agg(const uint32* __restrict__ XWu, const int* __restrict__ col,
                                             const int* __restrict__ off, const float* __restrict__ dinv,
                                             const float* __restrict__ bias, uint32* __restrict__ Hu) {
    int wid = (blockIdx.x * blockDim.x + threadIdx.x) >> 6;
    int lane = threadIdx.x & 63;
    if (wid >= N_NODES) return;
    int n = wid;
    AGG_BODY4
    if (half == 0) {
        float4 bb0 = ((const float4*)bias)[2 * fl];
        float4 bb1 = ((const float4*)bias)[2 * fl + 1];
        float r0 = fmaxf(a0 + bb0.x, 0.f), r1 = fmaxf(a1 + bb0.y, 0.f);
        float r2 = fmaxf(a2 + bb0.z, 0.f), r3 = fmaxf(a3 + bb0.w, 0.f);
        float r4 = fmaxf(a4 + bb1.x, 0.f), r5 = fmaxf(a5 + bb1.y, 0.f);
        float r6 = fmaxf(a6 + bb1.z, 0.f), r7 = fmaxf(a7 + bb1.w, 0.f);
        uint4 o;
        o.x = (uint32)f2b(r0) | ((uint32)f2b(r1) << 16);
        o.y = (uint32)f2b(r2) | ((uint32)f2b(r3) << 16);
        o.z = (uint32)f2b(r4) | ((uint32)f2b(r5) << 16);
        o.w = (uint32)f2b(r6) | ((uint32)f2b(r7) << 16);
        ((uint4*)Hu)[(size_t)n * 16 + fl] = o;
    }
}

// ---------------- layer-3 aggregation + relu + FC dot -> per-node scalar ----------------
__global__ __launch_bounds__(256) void k_agg_fc(const uint32* __restrict__ XWu, const int* __restrict__ col,
                                                const int* __restrict__ off, const float* __restrict__ dinv,
                                                const float* __restrict__ bias, const float* __restrict__ Wfc,
                                                float* __restrict__ nodeS) {
    int wid = (blockIdx.x * blockDim.x + threadIdx.x) >> 6;
    int lane = threadIdx.x & 63;
    if (wid >= N_NODES) return;
    int n = wid;
    AGG_BODY4
    float4 bb0 = ((const float4*)bias)[2 * fl];
    float4 bb1 = ((const float4*)bias)[2 * fl + 1];
    float4 wf0 = ((const float4*)Wfc)[2 * fl];
    float4 wf1 = ((const float4*)Wfc)[2 * fl + 1];
    float s = fmaxf(a0 + bb0.x, 0.f) * wf0.x + fmaxf(a1 + bb0.y, 0.f) * wf0.y
            + fmaxf(a2 + bb0.z, 0.f) * wf0.z + fmaxf(a3 + bb0.w, 0.f) * wf0.w
            + fmaxf(a4 + bb1.x, 0.f) * wf1.x + fmaxf(a5 + bb1.y, 0.f) * wf1.y
            + fmaxf(a6 + bb1.z, 0.f) * wf1.z + fmaxf(a7 + bb1.w, 0.f) * wf1.w;
    s += __shfl_xor(s, 8, 64);
    s += __shfl_xor(s, 4, 64);
    s += __shfl_xor(s, 2, 64);
    s += __shfl_xor(s, 1, 64);
    if (lane == 0) nodeS[n] = s;
}

// ---------------- segment mean over sorted batch + bias (one block per graph) ----------------
__device__ inline int lower_bound_dev(const int* a, int n, int key) {
    int lo = 0, hi = n;
    while (lo < hi) {
        int mid = (lo + hi) >> 1;
        if (a[mid] < key) lo = mid + 1; else hi = mid;
    }
    return lo;
}

__global__ __launch_bounds__(256) void k_pool(const float* __restrict__ nodeS, const int* __restrict__ batch,
                                              const float* __restrict__ bfc, float* __restrict__ out) {
    int g = blockIdx.x;
    int t = threadIdx.x;
    int lo = lower_bound_dev(batch, N_NODES, g);
    int hi = lower_bound_dev(batch, N_NODES, g + 1);
    float s = 0.f;
    for (int i = lo + t; i < hi; i += 256) s += nodeS[i];
    for (int d = 32; d > 0; d >>= 1) s += __shfl_down(s, d, 64);
    __shared__ float ws[4];
    int lane = t & 63, w = t >> 6;
    if (lane == 0) ws[w] = s;
    __syncthreads();
    if (t == 0) {
        float tot = ws[0] + ws[1] + ws[2] + ws[3];
        float cnt = (float)(hi - lo);
        out[g] = tot / fmaxf(cnt, 1.0f) + bfc[0];
    }
}

// ---------------- launch ----------------
extern "C" void kernel_launch(void* const* d_in, const int* in_sizes, int n_in,
                              void* d_out, int out_size, void* d_ws, size_t ws_size,
                              hipStream_t stream) {
    const float* x    = (const float*)d_in[0];
    const int*   ei   = (const int*)d_in[1];     // [2, E] : row0 = src, row1 = dst
    const int*   batch= (const int*)d_in[2];
    const float* W1   = (const float*)d_in[3];
    const float* b1   = (const float*)d_in[4];
    const float* W2   = (const float*)d_in[5];
    const float* b2   = (const float*)d_in[6];
    const float* W3   = (const float*)d_in[7];
    const float* b3   = (const float*)d_in[8];
    const float* Wfc  = (const float*)d_in[9];
    const float* bfc  = (const float*)d_in[10];
    float* out = (float*)d_out;

    const int* src = ei;
    const int* dst = ei + N_EDGES;

    // carve workspace (256B-aligned)
    char* p = (char*)d_ws;
    auto carve = [&](size_t bytes) { void* r = (void*)p; p += (bytes + 255) & ~(size_t)255; return r; };
    int*    cur       = (int*)   carve(sizeof(int) * NBUCK);                              // 1.6 KB
    uint32* bbuf      = (uint32*)carve(sizeof(uint32) * (size_t)NBUCK * BCAP);            // 7.2 MB
    float*  dinv      = (float*) carve(sizeof(float) * N_NODES);
    int*    offsets   = (int*)   carve(sizeof(int) * (N_NODES + 1));
    int*    col       = (int*)   carve(sizeof(int) * N_EDGES);
    ushort* XW        = (ushort*)carve(sizeof(short) * (size_t)N_NODES * NFEAT);
    ushort* H         = (ushort*)carve(sizeof(short) * (size_t)N_NODES * NFEAT);
    float*  nodeS     = (float*) carve(sizeof(float) * N_NODES);

    const int waveNodeBlocks = (N_NODES * 64 + 255) / 256;           // 25000
    const int gemmBlocks = (N_NODES + 64 * GEMM_TILES - 1) / (64 * GEMM_TILES);   // 391

    hipMemsetAsync(cur, 0, sizeof(int) * NBUCK, stream);
    k_scatter<<<SC_BLOCKS, 256, 0, stream>>>(src, dst, cur, bbuf);
    k_build<<<NBUCK, 256, 0, stream>>>(bbuf, cur, col, offsets, dinv);

    // layer 1 (x cast fused into GEMM A-load; W cast fused into staging)
    k_gemm_x<<<gemmBlocks, 512, 0, stream>>>(x, W1, XW, N_NODES);
    k_agg<<<waveNodeBlocks, 256, 0, stream>>>((const uint32*)XW, col, offsets, dinv, b1, (uint32*)H);
    // layer 2
    k_gemm<<<gemmBlocks, 512, 0, stream>>>(H, W2, XW, N_NODES);
    k_agg<<<waveNodeBlocks, 256, 0, stream>>>((const uint32*)XW, col, offsets, dinv, b2, (uint32*)H);
    // layer 3
    k_gemm<<<gemmBlocks, 512, 0, stream>>>(H, W3, XW, N_NODES);
    k_agg_fc<<<waveNodeBlocks, 256, 0, stream>>>((const uint32*)XW, col, offsets, dinv, b3, Wfc, nodeS);

    k_pool<<<N_GRAPHS, 256, 0, stream>>>(nodeS, batch, bfc, out);
}

// Round 14
// 383.506 us; speedup vs baseline: 1.0925x; 1.0925x over previous
//
#include <hip/hip_runtime.h>

#define N_NODES   100000
#define N_EDGES   1600000
#define NFEAT     128
#define N_GRAPHS  1024

// ---- bucketed CSR build (256-node buckets, block-local counting-sort scatter) ----
#define BSHIFT  8
#define BNODES  256
#define NBUCK   391                  // ceil(100000 / 256)
#define BCAP    4608                 // mean 4096 + 8 sigma
#define SC_EDGES 8192
#define SC_EPT   32                  // edges per thread (8192/256)
#define SC_BLOCKS 196                // ceil(1.6M / 8192)
#define BD_EPT   18                  // ceil(BCAP/256)

typedef unsigned int uint32;
typedef unsigned short ushort;
typedef __attribute__((ext_vector_type(8))) short short8;   // 8 bf16 (4 VGPRs)
typedef __attribute__((ext_vector_type(4))) float f32x4;

// fp32 -> bf16 bits, round-to-nearest-even (finite inputs)
__device__ inline ushort f2b(float f) {
    uint32 x = __float_as_uint(f);
    uint32 r = x + 0x7fffu + ((x >> 16) & 1u);
    return (ushort)(r >> 16);
}
__device__ inline float blo(uint32 u) { return __uint_as_float(u << 16); }
__device__ inline float bhi(uint32 u) { return __uint_as_float(u & 0xffff0000u); }

// ---------------- scatter: single-pass ticketed counting sort ----------------
// Pass 1 reads (src,dst) ONCE; the LDS histogram atomicAdd doubles as the edge's
// ticket (rank within its bin). After the scan, edges place at lofs[b]+ticket --
// no second global read, no second atomic round.
__global__ __launch_bounds__(256) void k_scatter(const int* __restrict__ src, const int* __restrict__ dst,
                                                 int* __restrict__ cur, uint32* __restrict__ bbuf) {
    __shared__ int hist[NBUCK];
    __shared__ int lofs[NBUCK];
    __shared__ int gbase[NBUCK];
    __shared__ int wsum[4];
    __shared__ uint32 sortedP[SC_EDGES];   // 32 KB
    __shared__ ushort sortedB[SC_EDGES];   // 16 KB
    int t = threadIdx.x;
    int e0 = blockIdx.x * SC_EDGES;
    int total = N_EDGES - e0; if (total > SC_EDGES) total = SC_EDGES; if (total < 0) total = 0;

    for (int i = t; i < NBUCK; i += 256) hist[i] = 0;
    __syncthreads();

    uint32 val[SC_EPT];
    int    meta[SC_EPT];    // (bucket << 13) | ticket
    #pragma unroll
    for (int k = 0; k < SC_EPT; ++k) {
        int i = t + k * 256;
        meta[k] = -1;
        if (i < total) {
            int s = src[e0 + i], d = dst[e0 + i];
            int b = d >> BSHIFT;
            int tk = atomicAdd(&hist[b], 1);
            val[k] = ((uint32)(d & (BNODES - 1)) << 17) | (uint32)s;
            meta[k] = (b << 13) | tk;
        }
    }
    __syncthreads();
    // scan of 391 bins (2/thread) + per-bin global reservation
    {
        int b0 = 2 * t, b1 = 2 * t + 1;
        int h0 = (b0 < NBUCK) ? hist[b0] : 0;
        int h1 = (b1 < NBUCK) ? hist[b1] : 0;
        int ts = h0 + h1;
        int lane = t & 63, w = t >> 6;
        int inc = ts;
        #pragma unroll
        for (int d = 1; d < 64; d <<= 1) {
            int u = __shfl_up(inc, d, 64);
            if (lane >= d) inc += u;
        }
        if (lane == 63) wsum[w] = inc;
        __syncthreads();
        int wpre = 0;
        for (int i = 0; i < w; ++i) wpre += wsum[i];
        int run = wpre + inc - ts;
        if (b0 < NBUCK) {
            lofs[b0] = run;
            if (h0) gbase[b0] = atomicAdd(&cur[b0], h0);
        }
        if (b1 < NBUCK) {
            lofs[b1] = run + h0;
            if (h1) gbase[b1] = atomicAdd(&cur[b1], h1);
        }
    }
    __syncthreads();
    // place into LDS at lofs[b] + ticket
    #pragma unroll
    for (int k = 0; k < SC_EPT; ++k) {
        if (meta[k] >= 0) {
            int b = meta[k] >> 13;
            int p = lofs[b] + (meta[k] & 0x1FFF);
            sortedP[p] = val[k];
            sortedB[p] = (ushort)b;
        }
    }
    __syncthreads();
    // burst write-out: contiguous runs per bucket
    for (int i = t; i < total; i += 256) {
        int b = sortedB[i];
        int addr = gbase[b] + (i - lofs[b]);
        if (addr < BCAP)
            bbuf[(size_t)b * BCAP + addr] = sortedP[i];
    }
}

// ---------------- per-bucket ticketed counting sort -> CSR col + offsets + dinv ----------------
__global__ __launch_bounds__(256) void k_build(const uint32* __restrict__ bbuf, const int* __restrict__ cur,
                                               int* __restrict__ col, int* __restrict__ offsets,
                                               float* __restrict__ dinv) {
    int b = blockIdx.x;
    __shared__ int hist[BNODES], excl[BNODES];
    __shared__ int wsum[4], wtot[4];
    __shared__ int sorted[BCAP];              // 18 KB
    __shared__ int sBase, sTotal;
    int t = threadIdx.x;
    // in-block bucket prefix: pre = sum_{i<b} min(cur[i],BCAP); tot = sum_all
    {
        int pre = 0, tot = 0;
        #pragma unroll
        for (int q = 0; q < 2; ++q) {
            int i = 2 * t + q;
            if (i < NBUCK) {
                int v = cur[i]; if (v > BCAP) v = BCAP;
                tot += v;
                if (i < b) pre += v;
            }
        }
        int lane = t & 63, w = t >> 6;
        #pragma unroll
        for (int d = 32; d > 0; d >>= 1) { pre += __shfl_down(pre, d, 64); tot += __shfl_down(tot, d, 64); }
        if (lane == 0) { wsum[w] = pre; wtot[w] = tot; }
        __syncthreads();
        if (t == 0) {
            sBase = wsum[0] + wsum[1] + wsum[2] + wsum[3];
            sTotal = wtot[0] + wtot[1] + wtot[2] + wtot[3];
        }
        hist[t] = 0;
    }
    __syncthreads();
    int base = sBase;
    if (b == NBUCK - 1 && t == 0) offsets[N_NODES] = sTotal;
    int cnt = cur[b]; if (cnt > BCAP) cnt = BCAP;
    const uint32* reg = bbuf + (size_t)b * BCAP;

    // single pass: read + ticket
    uint32 val[BD_EPT];
    int    meta[BD_EPT];   // (node << 16) | ticket
    #pragma unroll
    for (int k = 0; k < BD_EPT; ++k) {
        int i = t + k * 256;
        meta[k] = -1;
        if (i < cnt) {
            uint32 p = reg[i];
            int node = p >> 17;
            int tk = atomicAdd(&hist[node], 1);
            val[k] = p & 0x1FFFF;
            meta[k] = (node << 16) | tk;
        }
    }
    __syncthreads();
    // scan 256 node-counts -> excl; emit offsets + dinv
    {
        int c = hist[t];
        int lane = t & 63, w = t >> 6;
        int inc = c;
        #pragma unroll
        for (int d = 1; d < 64; d <<= 1) {
            int u = __shfl_up(inc, d, 64);
            if (lane >= d) inc += u;
        }
        if (lane == 63) wsum[w] = inc;
        __syncthreads();
        int wpre = 0;
        for (int i = 0; i < w; ++i) wpre += wsum[i];
        int e = wpre + inc - c;
        excl[t] = e;
        int node = (b << BSHIFT) + t;
        if (node < N_NODES) {
            offsets[node] = base + e;
            dinv[node] = rsqrtf((float)(c + 1));
        }
    }
    __syncthreads();
    #pragma unroll
    for (int k = 0; k < BD_EPT; ++k) {
        if (meta[k] >= 0) {
            int node = meta[k] >> 16;
            sorted[excl[node] + (meta[k] & 0xFFFF)] = (int)val[k];
        }
    }
    __syncthreads();
    for (int i = t; i < cnt; i += 256) col[base + i] = sorted[i];
}

// ---------------- cast + transpose W1,W2,W3 -> WT bf16 [layer][n][k] ----------------
__global__ __launch_bounds__(256) void k_castw(const float* __restrict__ W1, const float* __restrict__ W2,
                                               const float* __restrict__ W3, ushort* __restrict__ WT) {
    int i = blockIdx.x * blockDim.x + threadIdx.x;   // 3*16384
    if (i >= 3 * NFEAT * NFEAT) return;
    int l = i >> 14;
    int j = i & 16383;
    int n = j >> 7;
    int k = j & 127;
    const float* W = (l == 0) ? W1 : (l == 1) ? W2 : W3;
    WT[i] = f2b(W[k * NFEAT + n]);   // WT[l][n*128+k] = W[k][n]
}

// ---------------- bf16 MFMA GEMM: C[M,128] = A[M,128] @ W (r12 form) ----------------
// 512 threads, 8 waves x 16 rows = 128 rows/block. Epilogue via LDS C-tile.
#define WT_STRIDE 136
#define GEMM_EPILOGUE \
    __syncthreads(); \
    { \
        ushort* sC = sWT; \
        int colBase = lane & 15; \
        _Pragma("unroll") \
        for (int r = 0; r < 4; ++r) { \
            int lr = wave * 16 + kg * 4 + r; \
            _Pragma("unroll") \
            for (int nt = 0; nt < 8; ++nt) \
                sC[lr * NFEAT + nt * 16 + colBase] = f2b(acc[nt][r]); \
        } \
    } \
    __syncthreads(); \
    { \
        int rowBase = blockIdx.x * 128; \
        const float4* sC4 = (const float4*)sWT; \
        for (int i = t; i < 2048; i += 512) { \
            int row = i >> 4; \
            int gr = rowBase + row; \
            if (gr < M) ((float4*)(C + (size_t)gr * NFEAT))[i & 15] = sC4[i]; \
        } \
    }

__global__ __launch_bounds__(512) void k_gemm(const ushort* __restrict__ A,
                                              const ushort* __restrict__ WTl,
                                              ushort* __restrict__ C, int M) {
    __shared__ ushort sWT[NFEAT * WT_STRIDE];   // 34 KB
    int t = threadIdx.x;
    for (int i = t; i < NFEAT * 16; i += 512) {
        int n = i >> 4, c = i & 15;
        *(float4*)(sWT + n * WT_STRIDE + c * 8) = ((const float4*)WTl)[i];
    }
    int wave = t >> 6, lane = t & 63;
    int m0 = blockIdx.x * 128 + wave * 16;
    int mRow = m0 + (lane & 15);
    if (mRow >= M) mRow = M - 1;
    int kg = lane >> 4;
    const short8* Ap = (const short8*)(A + (size_t)mRow * NFEAT + kg * 8);
    short8 a0 = Ap[0];
    short8 a1 = Ap[4];
    short8 a2 = Ap[8];
    short8 a3 = Ap[12];
    __syncthreads();

    f32x4 acc[8];
    #pragma unroll
    for (int nt = 0; nt < 8; ++nt) acc[nt] = (f32x4){0.f, 0.f, 0.f, 0.f};

    #pragma unroll
    for (int nt = 0; nt < 8; ++nt) {
        int n = nt * 16 + (lane & 15);
        const short8* Bp = (const short8*)(sWT + n * WT_STRIDE + kg * 8);
        short8 b0 = Bp[0];
        short8 b1 = Bp[4];
        short8 b2 = Bp[8];
        short8 b3 = Bp[12];
        acc[nt] = __builtin_amdgcn_mfma_f32_16x16x32_bf16(a0, b0, acc[nt], 0, 0, 0);
        acc[nt] = __builtin_amdgcn_mfma_f32_16x16x32_bf16(a1, b1, acc[nt], 0, 0, 0);
        acc[nt] = __builtin_amdgcn_mfma_f32_16x16x32_bf16(a2, b2, acc[nt], 0, 0, 0);
        acc[nt] = __builtin_amdgcn_mfma_f32_16x16x32_bf16(a3, b3, acc[nt], 0, 0, 0);
    }
    GEMM_EPILOGUE
}

__device__ inline short8 cvt8(const float* p) {
    float4 v0 = ((const float4*)p)[0];
    float4 v1 = ((const float4*)p)[1];
    short8 r;
    r[0] = (short)f2b(v0.x); r[1] = (short)f2b(v0.y);
    r[2] = (short)f2b(v0.z); r[3] = (short)f2b(v0.w);
    r[4] = (short)f2b(v1.x); r[5] = (short)f2b(v1.y);
    r[6] = (short)f2b(v1.z); r[7] = (short)f2b(v1.w);
    return r;
}

__global__ __launch_bounds__(512) void k_gemm_x(const float* __restrict__ A,
                                                const ushort* __restrict__ WTl,
                                                ushort* __restrict__ C, int M) {
    __shared__ ushort sWT[NFEAT * WT_STRIDE];   // 34 KB
    int t = threadIdx.x;
    for (int i = t; i < NFEAT * 16; i += 512) {
        int n = i >> 4, c = i & 15;
        *(float4*)(sWT + n * WT_STRIDE + c * 8) = ((const float4*)WTl)[i];
    }
    int wave = t >> 6, lane = t & 63;
    int m0 = blockIdx.x * 128 + wave * 16;
    int mRow = m0 + (lane & 15);
    if (mRow >= M) mRow = M - 1;
    int kg = lane >> 4;
    const float* Ap = A + (size_t)mRow * NFEAT + kg * 8;
    short8 a0 = cvt8(Ap);
    short8 a1 = cvt8(Ap + 32);
    short8 a2 = cvt8(Ap + 64);
    short8 a3 = cvt8(Ap + 96);
    __syncthreads();

    f32x4 acc[8];
    #pragma unroll
    for (int nt = 0; nt < 8; ++nt) acc[nt] = (f32x4){0.f, 0.f, 0.f, 0.f};

    #pragma unroll
    for (int nt = 0; nt < 8; ++nt) {
        int n = nt * 16 + (lane & 15);
        const short8* Bp = (const short8*)(sWT + n * WT_STRIDE + kg * 8);
        short8 b0 = Bp[0];
        short8 b1 = Bp[4];
        short8 b2 = Bp[8];
        short8 b3 = Bp[12];
        acc[nt] = __builtin_amdgcn_mfma_f32_16x16x32_bf16(a0, b0, acc[nt], 0, 0, 0);
        acc[nt] = __builtin_amdgcn_mfma_f32_16x16x32_bf16(a1, b1, acc[nt], 0, 0, 0);
        acc[nt] = __builtin_amdgcn_mfma_f32_16x16x32_bf16(a2, b2, acc[nt], 0, 0, 0);
        acc[nt] = __builtin_amdgcn_mfma_f32_16x16x32_bf16(a3, b3, acc[nt], 0, 0, 0);
    }
    GEMM_EPILOGUE
}

// ---------------- aggregation core: 4 edges per uint4 gather instruction ----------------
#define AGG_BODY4 \
    float dn = dinv[n]; \
    int half = lane >> 4; \
    int fl = lane & 15; \
    const uint4* XW4 = (const uint4*)XWu; \
    uint4 sv = XW4[(size_t)n * 16 + fl]; \
    float ws = (half == 0) ? dn * dn : 0.f; \
    float a0 = ws * blo(sv.x), a1 = ws * bhi(sv.x); \
    float a2 = ws * blo(sv.y), a3 = ws * bhi(sv.y); \
    float a4 = ws * blo(sv.z), a5 = ws * bhi(sv.z); \
    float a6 = ws * blo(sv.w), a7 = ws * bhi(sv.w); \
    int e0 = off[n], e1 = off[n + 1]; \
    for (int base = e0; base < e1; base += 64) { \
        int len = e1 - base; if (len > 64) len = 64; \
        int cm = (lane < len) ? col[base + lane] : 0; \
        float wm = (lane < len) ? dn * dinv[cm] : 0.f; \
        int j = 0; \
        for (; j + 16 <= len; j += 16) { \
            uint4 u[4]; float w[4]; \
            _Pragma("unroll") \
            for (int p = 0; p < 4; ++p) { \
                int idx = j + 4 * p + half; \
                int cc = __shfl(cm, idx, 64); \
                w[p] = __shfl(wm, idx, 64); \
                u[p] = XW4[(size_t)cc * 16 + fl]; \
            } \
            _Pragma("unroll") \
            for (int p = 0; p < 4; ++p) { \
                a0 = fmaf(w[p], blo(u[p].x), a0); a1 = fmaf(w[p], bhi(u[p].x), a1); \
                a2 = fmaf(w[p], blo(u[p].y), a2); a3 = fmaf(w[p], bhi(u[p].y), a3); \
                a4 = fmaf(w[p], blo(u[p].z), a4); a5 = fmaf(w[p], bhi(u[p].z), a5); \
                a6 = fmaf(w[p], blo(u[p].w), a6); a7 = fmaf(w[p], bhi(u[p].w), a7); \
            } \
        } \
        for (; j < len; j += 4) { \
            int rem = len - j; \
            int idx = j + ((half < rem) ? half : 0); \
            int cc = __shfl(cm, idx, 64); \
            float ww = __shfl(wm, idx, 64); \
            if (half >= rem) ww = 0.f; \
            uint4 u = XW4[(size_t)cc * 16 + fl]; \
            a0 = fmaf(ww, blo(u.x), a0); a1 = fmaf(ww, bhi(u.x), a1); \
            a2 = fmaf(ww, blo(u.y), a2); a3 = fmaf(ww, bhi(u.y), a3); \
            a4 = fmaf(ww, blo(u.z), a4); a5 = fmaf(ww, bhi(u.z), a5); \
            a6 = fmaf(ww, blo(u.w), a6); a7 = fmaf(ww, bhi(u.w), a7); \
        } \
    } \
    a0 += __shfl_xor(a0, 32, 64); a0 += __shfl_xor(a0, 16, 64); \
    a1 += __shfl_xor(a1, 32, 64); a1 += __shfl_xor(a1, 16, 64); \
    a2 += __shfl_xor(a2, 32, 64); a2 += __shfl_xor(a2, 16, 64); \
    a3 += __shfl_xor(a3, 32, 64); a3 += __shfl_xor(a3, 16, 64); \
    a4 += __shfl_xor(a4, 32, 64); a4 += __shfl_xor(a4, 16, 64); \
    a5 += __shfl_xor(a5, 32, 64); a5 += __shfl_xor(a5, 16, 64); \
    a6 += __shfl_xor(a6, 32, 64); a6 += __shfl_xor(a6, 16, 64); \
    a7 += __shfl_xor(a7, 32, 64); a7 += __shfl_xor(a7, 16, 64);

__global__ __launch_bounds__(256) void k_agg(const uint32* __restrict__ XWu, const int* __restrict__ col,
                                             const int* __restrict__ off, const float* __restrict__ dinv,
                                             const float* __restrict__ bias, uint32* __restrict__ Hu) {
    int wid = (blockIdx.x * blockDim.x + threadIdx.x) >> 6;
    int lane = threadIdx.x & 63;
    if (wid >= N_NODES) return;
    int n = wid;
    AGG_BODY4
    if (half == 0) {
        float4 bb0 = ((const float4*)bias)[2 * fl];
        float4 bb1 = ((const float4*)bias)[2 * fl + 1];
        float r0 = fmaxf(a0 + bb0.x, 0.f), r1 = fmaxf(a1 + bb0.y, 0.f);
        float r2 = fmaxf(a2 + bb0.z, 0.f), r3 = fmaxf(a3 + bb0.w, 0.f);
        float r4 = fmaxf(a4 + bb1.x, 0.f), r5 = fmaxf(a5 + bb1.y, 0.f);
        float r6 = fmaxf(a6 + bb1.z, 0.f), r7 = fmaxf(a7 + bb1.w, 0.f);
        uint4 o;
        o.x = (uint32)f2b(r0) | ((uint32)f2b(r1) << 16);
        o.y = (uint32)f2b(r2) | ((uint32)f2b(r3) << 16);
        o.z = (uint32)f2b(r4) | ((uint32)f2b(r5) << 16);
        o.w = (uint32)f2b(r6) | ((uint32)f2b(r7) << 16);
        ((uint4*)Hu)[(size_t)n * 16 + fl] = o;
    }
}

// ---------------- layer-3 aggregation + relu + FC dot -> per-node scalar ----------------
__global__ __launch_bounds__(256) void k_agg_fc(const uint32* __restrict__ XWu, const int* __restrict__ col,
                                                const int* __restrict__ off, const float* __restrict__ dinv,
                                                const float* __restrict__ bias, const float* __restrict__ Wfc,
                                                float* __restrict__ nodeS) {
    int wid = (blockIdx.x * blockDim.x + threadIdx.x) >> 6;
    int lane = threadIdx.x & 63;
    if (wid >= N_NODES) return;
    int n = wid;
    AGG_BODY4
    float4 bb0 = ((const float4*)bias)[2 * fl];
    float4 bb1 = ((const float4*)bias)[2 * fl + 1];
    float4 wf0 = ((const float4*)Wfc)[2 * fl];
    float4 wf1 = ((const float4*)Wfc)[2 * fl + 1];
    float s = fmaxf(a0 + bb0.x, 0.f) * wf0.x + fmaxf(a1 + bb0.y, 0.f) * wf0.y
            + fmaxf(a2 + bb0.z, 0.f) * wf0.z + fmaxf(a3 + bb0.w, 0.f) * wf0.w
            + fmaxf(a4 + bb1.x, 0.f) * wf1.x + fmaxf(a5 + bb1.y, 0.f) * wf1.y
            + fmaxf(a6 + bb1.z, 0.f) * wf1.z + fmaxf(a7 + bb1.w, 0.f) * wf1.w;
    s += __shfl_xor(s, 8, 64);
    s += __shfl_xor(s, 4, 64);
    s += __shfl_xor(s, 2, 64);
    s += __shfl_xor(s, 1, 64);
    if (lane == 0) nodeS[n] = s;
}

// ---------------- segment mean over sorted batch + bias (one block per graph) ----------------
__device__ inline int lower_bound_dev(const int* a, int n, int key) {
    int lo = 0, hi = n;
    while (lo < hi) {
        int mid = (lo + hi) >> 1;
        if (a[mid] < key) lo = mid + 1; else hi = mid;
    }
    return lo;
}

__global__ __launch_bounds__(256) void k_pool(const float* __restrict__ nodeS, const int* __restrict__ batch,
                                              const float* __restrict__ bfc, float* __restrict__ out) {
    int g = blockIdx.x;
    int t = threadIdx.x;
    int lo = lower_bound_dev(batch, N_NODES, g);
    int hi = lower_bound_dev(batch, N_NODES, g + 1);
    float s = 0.f;
    for (int i = lo + t; i < hi; i += 256) s += nodeS[i];
    for (int d = 32; d > 0; d >>= 1) s += __shfl_down(s, d, 64);
    __shared__ float ws[4];
    int lane = t & 63, w = t >> 6;
    if (lane == 0) ws[w] = s;
    __syncthreads();
    if (t == 0) {
        float tot = ws[0] + ws[1] + ws[2] + ws[3];
        float cnt = (float)(hi - lo);
        out[g] = tot / fmaxf(cnt, 1.0f) + bfc[0];
    }
}

// ---------------- launch ----------------
extern "C" void kernel_launch(void* const* d_in, const int* in_sizes, int n_in,
                              void* d_out, int out_size, void* d_ws, size_t ws_size,
                              hipStream_t stream) {
    const float* x    = (const float*)d_in[0];
    const int*   ei   = (const int*)d_in[1];     // [2, E] : row0 = src, row1 = dst
    const int*   batch= (const int*)d_in[2];
    const float* W1   = (const float*)d_in[3];
    const float* b1   = (const float*)d_in[4];
    const float* W2   = (const float*)d_in[5];
    const float* b2   = (const float*)d_in[6];
    const float* W3   = (const float*)d_in[7];
    const float* b3   = (const float*)d_in[8];
    const float* Wfc  = (const float*)d_in[9];
    const float* bfc  = (const float*)d_in[10];
    float* out = (float*)d_out;

    const int* src = ei;
    const int* dst = ei + N_EDGES;

    // carve workspace (256B-aligned)
    char* p = (char*)d_ws;
    auto carve = [&](size_t bytes) { void* r = (void*)p; p += (bytes + 255) & ~(size_t)255; return r; };
    int*    cur       = (int*)   carve(sizeof(int) * NBUCK);                              // 1.6 KB
    uint32* bbuf      = (uint32*)carve(sizeof(uint32) * (size_t)NBUCK * BCAP);            // 7.2 MB
    float*  dinv      = (float*) carve(sizeof(float) * N_NODES);
    int*    offsets   = (int*)   carve(sizeof(int) * (N_NODES + 1));
    int*    col       = (int*)   carve(sizeof(int) * N_EDGES);
    ushort* XW        = (ushort*)carve(sizeof(short) * (size_t)N_NODES * NFEAT);
    ushort* H         = (ushort*)carve(sizeof(short) * (size_t)N_NODES * NFEAT);
    ushort* WT        = (ushort*)carve(sizeof(short) * 3 * NFEAT * NFEAT);
    float*  nodeS     = (float*) carve(sizeof(float) * N_NODES);

    const int waveNodeBlocks = (N_NODES * 64 + 255) / 256;   // 25000
    const int gemmBlocks = (N_NODES + 127) / 128;            // 782

    hipMemsetAsync(cur, 0, sizeof(int) * NBUCK, stream);
    k_scatter<<<SC_BLOCKS, 256, 0, stream>>>(src, dst, cur, bbuf);
    k_build<<<NBUCK, 256, 0, stream>>>(bbuf, cur, col, offsets, dinv);

    k_castw<<<(3 * NFEAT * NFEAT + 255) / 256, 256, 0, stream>>>(W1, W2, W3, WT);

    // layer 1 (cast fused into GEMM A-load)
    k_gemm_x<<<gemmBlocks, 512, 0, stream>>>(x, WT, XW, N_NODES);
    k_agg<<<waveNodeBlocks, 256, 0, stream>>>((const uint32*)XW, col, offsets, dinv, b1, (uint32*)H);
    // layer 2
    k_gemm<<<gemmBlocks, 512, 0, stream>>>(H, WT + NFEAT * NFEAT, XW, N_NODES);
    k_agg<<<waveNodeBlocks, 256, 0, stream>>>((const uint32*)XW, col, offsets, dinv, b2, (uint32*)H);
    // layer 3
    k_gemm<<<gemmBlocks, 512, 0, stream>>>(H, WT + 2 * NFEAT * NFEAT, XW, N_NODES);
    k_agg_fc<<<waveNodeBlocks, 256, 0, stream>>>((const uint32*)XW, col, offsets, dinv, b3, Wfc, nodeS);

    k_pool<<<N_GRAPHS, 256, 0, stream>>>(nodeS, batch, bfc, out);
}

// Round 15
// 372.282 us; speedup vs baseline: 1.1254x; 1.0302x over previous
//
#include <hip/hip_runtime.h>

#define N_NODES   100000
#define N_EDGES   1600000
#define NFEAT     128
#define N_GRAPHS  1024

// ---- bucketed CSR build ----
#define BSHIFT  8
#define BNODES  256
#define NBUCK   391                  // ceil(100000 / 256)
#define BCAP    4608                 // mean 4096 + 8 sigma
#define SC_EDGES 4096
#define SC_EPT   8                   // edges per thread (4096/512)
#define SC_BLOCKS 391                // ceil(1.6M / 4096)
#define BD_EPT   18                  // ceil(BCAP/256)

#define WT_STRIDE 136
#define GEMM_BLOCKS 782              // ceil(100000/128)

typedef unsigned int uint32;
typedef unsigned short ushort;
typedef __attribute__((ext_vector_type(8))) short short8;   // 8 bf16 (4 VGPRs)
typedef __attribute__((ext_vector_type(4))) float f32x4;

// fp32 -> bf16 bits, round-to-nearest-even (finite inputs)
__device__ inline ushort f2b(float f) {
    uint32 x = __float_as_uint(f);
    uint32 r = x + 0x7fffu + ((x >> 16) & 1u);
    return (ushort)(r >> 16);
}
__device__ inline float blo(uint32 u) { return __uint_as_float(u << 16); }
__device__ inline float bhi(uint32 u) { return __uint_as_float(u & 0xffff0000u); }

__device__ inline short8 cvt8(const float* p) {
    float4 v0 = ((const float4*)p)[0];
    float4 v1 = ((const float4*)p)[1];
    short8 r;
    r[0] = (short)f2b(v0.x); r[1] = (short)f2b(v0.y);
    r[2] = (short)f2b(v0.z); r[3] = (short)f2b(v0.w);
    r[4] = (short)f2b(v1.x); r[5] = (short)f2b(v1.y);
    r[6] = (short)f2b(v1.z); r[7] = (short)f2b(v1.w);
    return r;
}

// ---------------- cast+transpose W -> WT bf16 [layer][n][k]; also zero cur ----------------
__global__ __launch_bounds__(256) void k_castw(const float* __restrict__ W1, const float* __restrict__ W2,
                                               const float* __restrict__ W3, ushort* __restrict__ WT,
                                               int* __restrict__ cur) {
    int i = blockIdx.x * blockDim.x + threadIdx.x;   // 3*16384
    if (i < NBUCK) cur[i] = 0;
    if (i >= 3 * NFEAT * NFEAT) return;
    int l = i >> 14;
    int j = i & 16383;
    int n = j >> 7;
    int k = j & 127;
    const float* W = (l == 0) ? W1 : (l == 1) ? W2 : W3;
    WT[i] = f2b(W[k * NFEAT + n]);   // WT[l][n*128+k] = W[k][n]
}

// ---------------- phase 1: scatter (blocks 0..390) || layer-1 GEMM (blocks 391..1172) ----------------
struct SMemScatter {
    int hist[NBUCK], lofs[NBUCK], gbase[NBUCK];
    int wsum[4];
    uint32 sortedP[SC_EDGES];   // 16 KB
    ushort sortedB[SC_EDGES];   //  8 KB
};

__global__ __launch_bounds__(512) void k_phase1(const int* __restrict__ src, const int* __restrict__ dst,
                                                int* __restrict__ cur, uint32* __restrict__ bbuf,
                                                const float* __restrict__ A, const ushort* __restrict__ WTl,
                                                ushort* __restrict__ C, int M) {
    __shared__ __align__(16) char smem[NFEAT * WT_STRIDE * 2];   // 34 KB >= sizeof(SMemScatter)
    int t = threadIdx.x;
    if (blockIdx.x < SC_BLOCKS) {
        // ================== scatter: single-pass ticketed counting sort ==================
        SMemScatter& S = *(SMemScatter*)smem;
        int e0 = blockIdx.x * SC_EDGES;
        int total = N_EDGES - e0; if (total > SC_EDGES) total = SC_EDGES; if (total < 0) total = 0;
        for (int i = t; i < NBUCK; i += 512) S.hist[i] = 0;
        __syncthreads();
        uint32 val[SC_EPT];
        int    meta[SC_EPT];    // (bucket << 13) | ticket
        #pragma unroll
        for (int k = 0; k < SC_EPT; ++k) {
            int i = t + k * 512;
            meta[k] = -1;
            if (i < total) {
                int s = src[e0 + i], d = dst[e0 + i];
                int b = d >> BSHIFT;
                int tk = atomicAdd(&S.hist[b], 1);
                val[k] = ((uint32)(d & (BNODES - 1)) << 17) | (uint32)s;
                meta[k] = (b << 13) | tk;
            }
        }
        __syncthreads();
        // scan of 391 bins on first 256 threads (2/thread) + per-bin global reservation
        int inc = 0, ts = 0, h0 = 0;
        if (t < 256) {
            int b0 = 2 * t, b1 = 2 * t + 1;
            h0 = (b0 < NBUCK) ? S.hist[b0] : 0;
            int h1 = (b1 < NBUCK) ? S.hist[b1] : 0;
            ts = h0 + h1;
            int lane = t & 63;
            inc = ts;
            #pragma unroll
            for (int d = 1; d < 64; d <<= 1) {
                int u = __shfl_up(inc, d, 64);
                if (lane >= d) inc += u;
            }
            if (lane == 63) S.wsum[t >> 6] = inc;
        }
        __syncthreads();
        if (t < 256) {
            int w = t >> 6;
            int wpre = 0;
            for (int i = 0; i < w; ++i) wpre += S.wsum[i];
            int run = wpre + inc - ts;
            int b0 = 2 * t, b1 = 2 * t + 1;
            int h1 = ts - h0;
            if (b0 < NBUCK) {
                S.lofs[b0] = run;
                if (h0) S.gbase[b0] = atomicAdd(&cur[b0], h0);
            }
            if (b1 < NBUCK) {
                S.lofs[b1] = run + h0;
                if (h1) S.gbase[b1] = atomicAdd(&cur[b1], h1);
            }
        }
        __syncthreads();
        #pragma unroll
        for (int k = 0; k < SC_EPT; ++k) {
            if (meta[k] >= 0) {
                int b = meta[k] >> 13;
                int p = S.lofs[b] + (meta[k] & 0x1FFF);
                S.sortedP[p] = val[k];
                S.sortedB[p] = (ushort)b;
            }
        }
        __syncthreads();
        for (int i = t; i < total; i += 512) {
            int b = S.sortedB[i];
            int addr = S.gbase[b] + (i - S.lofs[b]);
            if (addr < BCAP)
                bbuf[(size_t)b * BCAP + addr] = S.sortedP[i];
        }
    } else {
        // ================== layer-1 GEMM (fp32 A, cast fused) ==================
        ushort* sWT = (ushort*)smem;
        int gb = blockIdx.x - SC_BLOCKS;
        for (int i = t; i < NFEAT * 16; i += 512) {
            int n = i >> 4, c = i & 15;
            *(float4*)(sWT + n * WT_STRIDE + c * 8) = ((const float4*)WTl)[i];
        }
        int wave = t >> 6, lane = t & 63;
        int m0 = gb * 128 + wave * 16;
        int mRow = m0 + (lane & 15);
        if (mRow >= M) mRow = M - 1;
        int kg = lane >> 4;
        const float* Ap = A + (size_t)mRow * NFEAT + kg * 8;
        short8 a0 = cvt8(Ap);
        short8 a1 = cvt8(Ap + 32);
        short8 a2 = cvt8(Ap + 64);
        short8 a3 = cvt8(Ap + 96);
        __syncthreads();

        f32x4 acc[8];
        #pragma unroll
        for (int nt = 0; nt < 8; ++nt) acc[nt] = (f32x4){0.f, 0.f, 0.f, 0.f};
        #pragma unroll
        for (int nt = 0; nt < 8; ++nt) {
            int n = nt * 16 + (lane & 15);
            const short8* Bp = (const short8*)(sWT + n * WT_STRIDE + kg * 8);
            short8 b0 = Bp[0];
            short8 b1 = Bp[4];
            short8 b2 = Bp[8];
            short8 b3 = Bp[12];
            acc[nt] = __builtin_amdgcn_mfma_f32_16x16x32_bf16(a0, b0, acc[nt], 0, 0, 0);
            acc[nt] = __builtin_amdgcn_mfma_f32_16x16x32_bf16(a1, b1, acc[nt], 0, 0, 0);
            acc[nt] = __builtin_amdgcn_mfma_f32_16x16x32_bf16(a2, b2, acc[nt], 0, 0, 0);
            acc[nt] = __builtin_amdgcn_mfma_f32_16x16x32_bf16(a3, b3, acc[nt], 0, 0, 0);
        }
        __syncthreads();
        {
            int colBase = lane & 15;
            #pragma unroll
            for (int r = 0; r < 4; ++r) {
                int lr = wave * 16 + kg * 4 + r;
                #pragma unroll
                for (int nt = 0; nt < 8; ++nt)
                    sWT[lr * NFEAT + nt * 16 + colBase] = f2b(acc[nt][r]);
            }
        }
        __syncthreads();
        {
            int rowBase = gb * 128;
            const float4* sC4 = (const float4*)sWT;
            for (int i = t; i < 2048; i += 512) {
                int row = i >> 4;
                int gr = rowBase + row;
                if (gr < M) ((float4*)(C + (size_t)gr * NFEAT))[i & 15] = sC4[i];
            }
        }
    }
}

// ---------------- per-bucket ticketed counting sort -> CSR col + offsets + dinv ----------------
__global__ __launch_bounds__(256) void k_build(const uint32* __restrict__ bbuf, const int* __restrict__ cur,
                                               int* __restrict__ col, int* __restrict__ offsets,
                                               float* __restrict__ dinv) {
    int b = blockIdx.x;
    __shared__ int hist[BNODES], excl[BNODES];
    __shared__ int wsum[4], wtot[4];
    __shared__ int sorted[BCAP];              // 18 KB
    __shared__ int sBase, sTotal;
    int t = threadIdx.x;
    {
        int pre = 0, tot = 0;
        #pragma unroll
        for (int q = 0; q < 2; ++q) {
            int i = 2 * t + q;
            if (i < NBUCK) {
                int v = cur[i]; if (v > BCAP) v = BCAP;
                tot += v;
                if (i < b) pre += v;
            }
        }
        int lane = t & 63, w = t >> 6;
        #pragma unroll
        for (int d = 32; d > 0; d >>= 1) { pre += __shfl_down(pre, d, 64); tot += __shfl_down(tot, d, 64); }
        if (lane == 0) { wsum[w] = pre; wtot[w] = tot; }
        __syncthreads();
        if (t == 0) {
            sBase = wsum[0] + wsum[1] + wsum[2] + wsum[3];
            sTotal = wtot[0] + wtot[1] + wtot[2] + wtot[3];
        }
        hist[t] = 0;
    }
    __syncthreads();
    int base = sBase;
    if (b == NBUCK - 1 && t == 0) offsets[N_NODES] = sTotal;
    int cnt = cur[b]; if (cnt > BCAP) cnt = BCAP;
    const uint32* reg = bbuf + (size_t)b * BCAP;

    uint32 val[BD_EPT];
    int    meta[BD_EPT];   // (node << 16) | ticket
    #pragma unroll
    for (int k = 0; k < BD_EPT; ++k) {
        int i = t + k * 256;
        meta[k] = -1;
        if (i < cnt) {
            uint32 p = reg[i];
            int node = p >> 17;
            int tk = atomicAdd(&hist[node], 1);
            val[k] = p & 0x1FFFF;
            meta[k] = (node << 16) | tk;
        }
    }
    __syncthreads();
    {
        int c = hist[t];
        int lane = t & 63, w = t >> 6;
        int inc = c;
        #pragma unroll
        for (int d = 1; d < 64; d <<= 1) {
            int u = __shfl_up(inc, d, 64);
            if (lane >= d) inc += u;
        }
        if (lane == 63) wsum[w] = inc;
        __syncthreads();
        int wpre = 0;
        for (int i = 0; i < w; ++i) wpre += wsum[i];
        int e = wpre + inc - c;
        excl[t] = e;
        int node = (b << BSHIFT) + t;
        if (node < N_NODES) {
            offsets[node] = base + e;
            dinv[node] = rsqrtf((float)(c + 1));
        }
    }
    __syncthreads();
    #pragma unroll
    for (int k = 0; k < BD_EPT; ++k) {
        if (meta[k] >= 0) {
            int node = meta[k] >> 16;
            sorted[excl[node] + (meta[k] & 0xFFFF)] = (int)val[k];
        }
    }
    __syncthreads();
    for (int i = t; i < cnt; i += 256) col[base + i] = sorted[i];
}

// ---------------- bf16 MFMA GEMM (layers 2,3): C[M,128] = A[M,128] @ W ----------------
__global__ __launch_bounds__(512) void k_gemm(const ushort* __restrict__ A,
                                              const ushort* __restrict__ WTl,
                                              ushort* __restrict__ C, int M) {
    __shared__ ushort sWT[NFEAT * WT_STRIDE];   // 34 KB
    int t = threadIdx.x;
    for (int i = t; i < NFEAT * 16; i += 512) {
        int n = i >> 4, c = i & 15;
        *(float4*)(sWT + n * WT_STRIDE + c * 8) = ((const float4*)WTl)[i];
    }
    int wave = t >> 6, lane = t & 63;
    int m0 = blockIdx.x * 128 + wave * 16;
    int mRow = m0 + (lane & 15);
    if (mRow >= M) mRow = M - 1;
    int kg = lane >> 4;
    const short8* Ap = (const short8*)(A + (size_t)mRow * NFEAT + kg * 8);
    short8 a0 = Ap[0];
    short8 a1 = Ap[4];
    short8 a2 = Ap[8];
    short8 a3 = Ap[12];
    __syncthreads();

    f32x4 acc[8];
    #pragma unroll
    for (int nt = 0; nt < 8; ++nt) acc[nt] = (f32x4){0.f, 0.f, 0.f, 0.f};
    #pragma unroll
    for (int nt = 0; nt < 8; ++nt) {
        int n = nt * 16 + (lane & 15);
        const short8* Bp = (const short8*)(sWT + n * WT_STRIDE + kg * 8);
        short8 b0 = Bp[0];
        short8 b1 = Bp[4];
        short8 b2 = Bp[8];
        short8 b3 = Bp[12];
        acc[nt] = __builtin_amdgcn_mfma_f32_16x16x32_bf16(a0, b0, acc[nt], 0, 0, 0);
        acc[nt] = __builtin_amdgcn_mfma_f32_16x16x32_bf16(a1, b1, acc[nt], 0, 0, 0);
        acc[nt] = __builtin_amdgcn_mfma_f32_16x16x32_bf16(a2, b2, acc[nt], 0, 0, 0);
        acc[nt] = __builtin_amdgcn_mfma_f32_16x16x32_bf16(a3, b3, acc[nt], 0, 0, 0);
    }
    __syncthreads();
    {
        int colBase = lane & 15;
        #pragma unroll
        for (int r = 0; r < 4; ++r) {
            int lr = wave * 16 + kg * 4 + r;
            #pragma unroll
            for (int nt = 0; nt < 8; ++nt)
                sWT[lr * NFEAT + nt * 16 + colBase] = f2b(acc[nt][r]);
        }
    }
    __syncthreads();
    {
        int rowBase = blockIdx.x * 128;
        const float4* sC4 = (const float4*)sWT;
        for (int i = t; i < 2048; i += 512) {
            int row = i >> 4;
            int gr = rowBase + row;
            if (gr < M) ((float4*)(C + (size_t)gr * NFEAT))[i & 15] = sC4[i];
        }
    }
}

// ---------------- aggregation core: 4 edges per uint4 gather instruction ----------------
#define AGG_BODY4 \
    float dn = dinv[n]; \
    int half = lane >> 4; \
    int fl = lane & 15; \
    const uint4* XW4 = (const uint4*)XWu; \
    uint4 sv = XW4[(size_t)n * 16 + fl]; \
    float ws = (half == 0) ? dn * dn : 0.f; \
    float a0 = ws * blo(sv.x), a1 = ws * bhi(sv.x); \
    float a2 = ws * blo(sv.y), a3 = ws * bhi(sv.y); \
    float a4 = ws * blo(sv.z), a5 = ws * bhi(sv.z); \
    float a6 = ws * blo(sv.w), a7 = ws * bhi(sv.w); \
    int e0 = off[n], e1 = off[n + 1]; \
    for (int base = e0; base < e1; base += 64) { \
        int len = e1 - base; if (len > 64) len = 64; \
        int cm = (lane < len) ? col[base + lane] : 0; \
        float wm = (lane < len) ? dn * dinv[cm] : 0.f; \
        int j = 0; \
        for (; j + 16 <= len; j += 16) { \
            uint4 u[4]; float w[4]; \
            _Pragma("unroll") \
            for (int p = 0; p < 4; ++p) { \
                int idx = j + 4 * p + half; \
                int cc = __shfl(cm, idx, 64); \
                w[p] = __shfl(wm, idx, 64); \
                u[p] = XW4[(size_t)cc * 16 + fl]; \
            } \
            _Pragma("unroll") \
            for (int p = 0; p < 4; ++p) { \
                a0 = fmaf(w[p], blo(u[p].x), a0); a1 = fmaf(w[p], bhi(u[p].x), a1); \
                a2 = fmaf(w[p], blo(u[p].y), a2); a3 = fmaf(w[p], bhi(u[p].y), a3); \
                a4 = fmaf(w[p], blo(u[p].z), a4); a5 = fmaf(w[p], bhi(u[p].z), a5); \
                a6 = fmaf(w[p], blo(u[p].w), a6); a7 = fmaf(w[p], bhi(u[p].w), a7); \
            } \
        } \
        for (; j < len; j += 4) { \
            int rem = len - j; \
            int idx = j + ((half < rem) ? half : 0); \
            int cc = __shfl(cm, idx, 64); \
            float ww = __shfl(wm, idx, 64); \
            if (half >= rem) ww = 0.f; \
            uint4 u = XW4[(size_t)cc * 16 + fl]; \
            a0 = fmaf(ww, blo(u.x), a0); a1 = fmaf(ww, bhi(u.x), a1); \
            a2 = fmaf(ww, blo(u.y), a2); a3 = fmaf(ww, bhi(u.y), a3); \
            a4 = fmaf(ww, blo(u.z), a4); a5 = fmaf(ww, bhi(u.z), a5); \
            a6 = fmaf(ww, blo(u.w), a6); a7 = fmaf(ww, bhi(u.w), a7); \
        } \
    } \
    a0 += __shfl_xor(a0, 32, 64); a0 += __shfl_xor(a0, 16, 64); \
    a1 += __shfl_xor(a1, 32, 64); a1 += __shfl_xor(a1, 16, 64); \
    a2 += __shfl_xor(a2, 32, 64); a2 += __shfl_xor(a2, 16, 64); \
    a3 += __shfl_xor(a3, 32, 64); a3 += __shfl_xor(a3, 16, 64); \
    a4 += __shfl_xor(a4, 32, 64); a4 += __shfl_xor(a4, 16, 64); \
    a5 += __shfl_xor(a5, 32, 64); a5 += __shfl_xor(a5, 16, 64); \
    a6 += __shfl_xor(a6, 32, 64); a6 += __shfl_xor(a6, 16, 64); \
    a7 += __shfl_xor(a7, 32, 64); a7 += __shfl_xor(a7, 16, 64);

__global__ __launch_bounds__(256) void k_agg(const uint32* __restrict__ XWu, const int* __restrict__ col,
                                             const int* __restrict__ off, const float* __restrict__ dinv,
                                             const float* __restrict__ bias, uint32* __restrict__ Hu) {
    int wid = (blockIdx.x * blockDim.x + threadIdx.x) >> 6;
    int lane = threadIdx.x & 63;
    if (wid >= N_NODES) return;
    int n = wid;
    AGG_BODY4
    if (half == 0) {
        float4 bb0 = ((const float4*)bias)[2 * fl];
        float4 bb1 = ((const float4*)bias)[2 * fl + 1];
        float r0 = fmaxf(a0 + bb0.x, 0.f), r1 = fmaxf(a1 + bb0.y, 0.f);
        float r2 = fmaxf(a2 + bb0.z, 0.f), r3 = fmaxf(a3 + bb0.w, 0.f);
        float r4 = fmaxf(a4 + bb1.x, 0.f), r5 = fmaxf(a5 + bb1.y, 0.f);
        float r6 = fmaxf(a6 + bb1.z, 0.f), r7 = fmaxf(a7 + bb1.w, 0.f);
        uint4 o;
        o.x = (uint32)f2b(r0) | ((uint32)f2b(r1) << 16);
        o.y = (uint32)f2b(r2) | ((uint32)f2b(r3) << 16);
        o.z = (uint32)f2b(r4) | ((uint32)f2b(r5) << 16);
        o.w = (uint32)f2b(r6) | ((uint32)f2b(r7) << 16);
        ((uint4*)Hu)[(size_t)n * 16 + fl] = o;
    }
}

__global__ __launch_bounds__(256) void k_agg_fc(const uint32* __restrict__ XWu, const int* __restrict__ col,
                                                const int* __restrict__ off, const float* __restrict__ dinv,
                                                const float* __restrict__ bias, const float* __restrict__ Wfc,
                                                float* __restrict__ nodeS) {
    int wid = (blockIdx.x * blockDim.x + threadIdx.x) >> 6;
    int lane = threadIdx.x & 63;
    if (wid >= N_NODES) return;
    int n = wid;
    AGG_BODY4
    float4 bb0 = ((const float4*)bias)[2 * fl];
    float4 bb1 = ((const float4*)bias)[2 * fl + 1];
    float4 wf0 = ((const float4*)Wfc)[2 * fl];
    float4 wf1 = ((const float4*)Wfc)[2 * fl + 1];
    float s = fmaxf(a0 + bb0.x, 0.f) * wf0.x + fmaxf(a1 + bb0.y, 0.f) * wf0.y
            + fmaxf(a2 + bb0.z, 0.f) * wf0.z + fmaxf(a3 + bb0.w, 0.f) * wf0.w
            + fmaxf(a4 + bb1.x, 0.f) * wf1.x + fmaxf(a5 + bb1.y, 0.f) * wf1.y
            + fmaxf(a6 + bb1.z, 0.f) * wf1.z + fmaxf(a7 + bb1.w, 0.f) * wf1.w;
    s += __shfl_xor(s, 8, 64);
    s += __shfl_xor(s, 4, 64);
    s += __shfl_xor(s, 2, 64);
    s += __shfl_xor(s, 1, 64);
    if (lane == 0) nodeS[n] = s;
}

// ---------------- segment mean over sorted batch + bias (one block per graph) ----------------
__device__ inline int lower_bound_dev(const int* a, int n, int key) {
    int lo = 0, hi = n;
    while (lo < hi) {
        int mid = (lo + hi) >> 1;
        if (a[mid] < key) lo = mid + 1; else hi = mid;
    }
    return lo;
}

__global__ __launch_bounds__(256) void k_pool(const float* __restrict__ nodeS, const int* __restrict__ batch,
                                              const float* __restrict__ bfc, float* __restrict__ out) {
    int g = blockIdx.x;
    int t = threadIdx.x;
    int lo = lower_bound_dev(batch, N_NODES, g);
    int hi = lower_bound_dev(batch, N_NODES, g + 1);
    float s = 0.f;
    for (int i = lo + t; i < hi; i += 256) s += nodeS[i];
    for (int d = 32; d > 0; d >>= 1) s += __shfl_down(s, d, 64);
    __shared__ float ws[4];
    int lane = t & 63, w = t >> 6;
    if (lane == 0) ws[w] = s;
    __syncthreads();
    if (t == 0) {
        float tot = ws[0] + ws[1] + ws[2] + ws[3];
        float cnt = (float)(hi - lo);
        out[g] = tot / fmaxf(cnt, 1.0f) + bfc[0];
    }
}

// ---------------- launch ----------------
extern "C" void kernel_launch(void* const* d_in, const int* in_sizes, int n_in,
                              void* d_out, int out_size, void* d_ws, size_t ws_size,
                              hipStream_t stream) {
    const float* x    = (const float*)d_in[0];
    const int*   ei   = (const int*)d_in[1];     // [2, E] : row0 = src, row1 = dst
    const int*   batch= (const int*)d_in[2];
    const float* W1   = (const float*)d_in[3];
    const float* b1   = (const float*)d_in[4];
    const float* W2   = (const float*)d_in[5];
    const float* b2   = (const float*)d_in[6];
    const float* W3   = (const float*)d_in[7];
    const float* b3   = (const float*)d_in[8];
    const float* Wfc  = (const float*)d_in[9];
    const float* bfc  = (const float*)d_in[10];
    float* out = (float*)d_out;

    const int* src = ei;
    const int* dst = ei + N_EDGES;

    // carve workspace (256B-aligned)
    char* p = (char*)d_ws;
    auto carve = [&](size_t bytes) { void* r = (void*)p; p += (bytes + 255) & ~(size_t)255; return r; };
    int*    cur       = (int*)   carve(sizeof(int) * NBUCK);
    uint32* bbuf      = (uint32*)carve(sizeof(uint32) * (size_t)NBUCK * BCAP);            // 7.2 MB
    float*  dinv      = (float*) carve(sizeof(float) * N_NODES);
    int*    offsets   = (int*)   carve(sizeof(int) * (N_NODES + 1));
    int*    col       = (int*)   carve(sizeof(int) * N_EDGES);
    ushort* XW        = (ushort*)carve(sizeof(short) * (size_t)N_NODES * NFEAT);
    ushort* H         = (ushort*)carve(sizeof(short) * (size_t)N_NODES * NFEAT);
    ushort* WT        = (ushort*)carve(sizeof(short) * 3 * NFEAT * NFEAT);
    float*  nodeS     = (float*) carve(sizeof(float) * N_NODES);

    const int waveNodeBlocks = (N_NODES * 64 + 255) / 256;   // 25000

    k_castw<<<(3 * NFEAT * NFEAT + 255) / 256, 256, 0, stream>>>(W1, W2, W3, WT, cur);
    // phase 1: scatter || layer-1 GEMM (independent work co-scheduled)
    k_phase1<<<SC_BLOCKS + GEMM_BLOCKS, 512, 0, stream>>>(src, dst, cur, bbuf, x, WT, XW, N_NODES);
    k_build<<<NBUCK, 256, 0, stream>>>(bbuf, cur, col, offsets, dinv);

    k_agg<<<waveNodeBlocks, 256, 0, stream>>>((const uint32*)XW, col, offsets, dinv, b1, (uint32*)H);
    // layer 2
    k_gemm<<<GEMM_BLOCKS, 512, 0, stream>>>(H, WT + NFEAT * NFEAT, XW, N_NODES);
    k_agg<<<waveNodeBlocks, 256, 0, stream>>>((const uint32*)XW, col, offsets, dinv, b2, (uint32*)H);
    // layer 3
    k_gemm<<<GEMM_BLOCKS, 512, 0, stream>>>(H, WT + 2 * NFEAT * NFEAT, XW, N_NODES);
    k_agg_fc<<<waveNodeBlocks, 256, 0, stream>>>((const uint32*)XW, col, offsets, dinv, b3, Wfc, nodeS);

    k_pool<<<N_GRAPHS, 256, 0, stream>>>(nodeS, batch, bfc, out);
}